// Round 1
// 715.197 us; speedup vs baseline: 1.2092x; 1.2092x over previous
//
#include <hip/hip_runtime.h>
#include <cstdint>
#include <cstddef>

#define M_DIM 2048
#define N_DIM 4096
#define K_DIM 20000
#define KP    20480                 /* K padded to multiple of 64 (zero-filled) */
#define KZ    10240                 /* K per split-K plane (2 planes) */
#define GSTEPS 160                  /* KZ / 64 */
#define WBT_BYTES  167772160UL      /* 4096*20480*2 : bf16 W^T (N x KP) */
#define XB_OFFSET  167772160UL      /* bf16 x (M x KP) after Wbt */
#define CP_OFFSET  251658240UL      /* 2x fp32 C-partials after xb */

typedef __attribute__((ext_vector_type(8))) short short8;
typedef __attribute__((ext_vector_type(4))) float float4v;
typedef __attribute__((ext_vector_type(8))) unsigned short ushort8;

__device__ __forceinline__ unsigned short f2bf_rne(float f) {
    union { float f; unsigned int u; } v; v.f = f;
    unsigned int u = v.u;
    u += 0x7FFFu + ((u >> 16) & 1u);   // round-to-nearest-even
    return (unsigned short)(u >> 16);
}

__device__ __forceinline__ float bf2f(unsigned short h) {
    union { unsigned int u; float f; } v;
    v.u = ((unsigned int)h) << 16;
    return v.f;
}

__device__ __forceinline__ void gload_lds16(const void* g, void* l) {
    __builtin_amdgcn_global_load_lds(
        (const __attribute__((address_space(1))) void*)g,
        (__attribute__((address_space(3))) void*)l, 16, 0, 0);
}

// ---- 1. scatter-add COO directly into bf16 W^T (N_DIM x KP row-major) ----
__global__ void scatter_bf16_kernel(const float* __restrict__ kv,
                                    const int* __restrict__ ind,
                                    unsigned int* __restrict__ W, int nnz) {
    int t = blockIdx.x * blockDim.x + threadIdx.x;
    if (t >= nnz) return;
    int r = ind[2 * t];      // input_dim index (K)
    int c = ind[2 * t + 1];  // units index (N)
    float v = kv[t];
    size_t elem = (size_t)c * KP + r;      // bf16 element index in W^T
    unsigned int* word = &W[elem >> 1];
    const bool hi = (elem & 1) != 0;       // KP even -> rows never straddle words
    unsigned int old = __atomic_load_n(word, __ATOMIC_RELAXED);
    unsigned int assumed;
    do {
        assumed = old;
        unsigned short h = hi ? (unsigned short)(assumed >> 16)
                              : (unsigned short)(assumed & 0xFFFFu);
        unsigned short nh = f2bf_rne(bf2f(h) + v);
        unsigned int nw = hi ? ((assumed & 0x0000FFFFu) | ((unsigned int)nh << 16))
                             : ((assumed & 0xFFFF0000u) | (unsigned int)nh);
        old = atomicCAS(word, assumed, nw);
    } while (old != assumed);
}

// ---- 2. fp32 -> bf16 convert for x, writes K-pad zeros itself ----
// one thread per 8 elements of the PADDED row: 2560 vec8-slots/row, 2500 real.
__global__ void convert_kernel(const float* __restrict__ src,
                               unsigned short* __restrict__ dst) {
    size_t t = (size_t)blockIdx.x * 256 + threadIdx.x;
    int row = (int)(t / 2560);
    int c8  = (int)(t % 2560);
    ushort8 o;
    if (c8 < 2500) {
        const float4* sv = (const float4*)(src + (size_t)row * K_DIM + (size_t)c8 * 8);
        float4 a = sv[0];
        float4 b = sv[1];
        o[0] = f2bf_rne(a.x); o[1] = f2bf_rne(a.y);
        o[2] = f2bf_rne(a.z); o[3] = f2bf_rne(a.w);
        o[4] = f2bf_rne(b.x); o[5] = f2bf_rne(b.y);
        o[6] = f2bf_rne(b.z); o[7] = f2bf_rne(b.w);
    } else {
        o = (ushort8)0;
    }
    *(ushort8*)(dst + (size_t)row * KP + (size_t)c8 * 8) = o;
}

// ---- 3. 256x256-tile split-K=2 GEMM partial, 8-wave deep-pipelined ----
// A: M x KP bf16 row-major, Bt: N x KP bf16 row-major.
// 512 thr = 8 waves (2Mx4N), per-wave 128x64 via 16x16x32 MFMA, BK=64.
// LDS 128 KiB: 2 bufs x (A 32KB + B 32KB), XOR-swizzled slots (s ^= row&7)
// applied on the GLOBAL source of global_load_lds (linear LDS dest) and on
// the ds_read address -> conflict-free b128 reads (2 lanes/bank, free).
// Counted vmcnt(8): 8 loads stay in flight across barriers (never drain to 0).
__global__ __launch_bounds__(512, 2) void gemm256_kernel(
    const unsigned short* __restrict__ A,
    const unsigned short* __restrict__ Bt,
    float* __restrict__ Cp) {

    __shared__ unsigned short L[65536];    // 131072 B

    const int t    = threadIdx.x;
    const int w    = t >> 6;
    const int l    = t & 63;
    const int quad = l >> 4;
    const int r16  = l & 15;
    const int wm   = w >> 2;               // 0..1
    const int wn   = w & 3;                // 0..3

    const int m0 = blockIdx.y * 256;
    const int n0 = blockIdx.x * 256;
    const size_t k0 = (size_t)blockIdx.z * KZ;

    // staging: lane l covers LDS row rst+?? slot (l&7); fetch global slot
    // (l&7)^(l>>3) so that LDS(row, s) holds global chunk s^(row&7).
    const int sl  = (l & 7) ^ (l >> 3);
    const int rst = w * 8 + (l >> 3);      // 0..63
    const unsigned short* gA[4];
    const unsigned short* gB[4];
#pragma unroll
    for (int j = 0; j < 4; ++j) {
        gA[j] = A  + (size_t)(m0 + j * 64 + rst) * KP + k0 + sl * 8;
        gB[j] = Bt + (size_t)(n0 + j * 64 + rst) * KP + k0 + sl * 8;
    }
    char* Lb = (char*)L;

    auto STAGE = [&](int cb) {
#pragma unroll
        for (int j = 0; j < 4; ++j) {
            gload_lds16(gA[j], Lb + cb + j * 8192 + (w << 10));
            gload_lds16(gB[j], Lb + cb + 32768 + j * 8192 + (w << 10));
            gA[j] += 64; gB[j] += 64;
        }
    };

    // ds_read byte offsets: row*128 + ((chunk ^ (row&7))*16), chunk = kh*4+quad
    const int h   = r16 & 7;
    const int so0 = ((quad ^ h) << 4);          // kh = 0
    const int so1 = (((4 | quad) ^ h) << 4);    // kh = 1
    const int arow = wm * 16384 + r16 * 128;    // + i*2048
    const int brow = wn * 8192  + r16 * 128;    // + j*2048

    float4v acc[8][4];
#pragma unroll
    for (int i = 0; i < 8; ++i)
#pragma unroll
        for (int j = 0; j < 4; ++j)
            acc[i][j] = (float4v){0.f, 0.f, 0.f, 0.f};

    // prologue: stage step0 -> buf0, step1 -> buf1; wait step0 only.
    STAGE(0);
    STAGE(65536);
    asm volatile("s_waitcnt vmcnt(8)" ::: "memory");
    __builtin_amdgcn_s_barrier();

    for (int ks = 0; ks < GSTEPS; ++ks) {
        const int cb = (ks & 1) << 16;
        const char* Ab = Lb + cb;
        const char* Bb = Lb + cb + 32768;

        short8 bf0[4], bf1[4], afA[4], afB[4];

        // phase 0: (mh0, kh0) — reads 8, mfma 16
#pragma unroll
        for (int j = 0; j < 4; ++j) bf0[j] = *(const short8*)(Bb + brow + j * 2048 + so0);
#pragma unroll
        for (int i = 0; i < 4; ++i) afA[i] = *(const short8*)(Ab + arow + i * 2048 + so0);
        __builtin_amdgcn_s_setprio(1);
#pragma unroll
        for (int i = 0; i < 4; ++i)
#pragma unroll
            for (int j = 0; j < 4; ++j)
                acc[i][j] = __builtin_amdgcn_mfma_f32_16x16x32_bf16(afA[i], bf0[j], acc[i][j], 0, 0, 0);
        __builtin_amdgcn_s_setprio(0);

        // phase 1: (mh0, kh1)
#pragma unroll
        for (int j = 0; j < 4; ++j) bf1[j] = *(const short8*)(Bb + brow + j * 2048 + so1);
#pragma unroll
        for (int i = 0; i < 4; ++i) afB[i] = *(const short8*)(Ab + arow + i * 2048 + so1);
        __builtin_amdgcn_s_setprio(1);
#pragma unroll
        for (int i = 0; i < 4; ++i)
#pragma unroll
            for (int j = 0; j < 4; ++j)
                acc[i][j] = __builtin_amdgcn_mfma_f32_16x16x32_bf16(afB[i], bf1[j], acc[i][j], 0, 0, 0);
        __builtin_amdgcn_s_setprio(0);

        // phase 2: (mh1, kh0)
#pragma unroll
        for (int i = 0; i < 4; ++i) afA[i] = *(const short8*)(Ab + arow + (i + 4) * 2048 + so0);
        __builtin_amdgcn_s_setprio(1);
#pragma unroll
        for (int i = 0; i < 4; ++i)
#pragma unroll
            for (int j = 0; j < 4; ++j)
                acc[i + 4][j] = __builtin_amdgcn_mfma_f32_16x16x32_bf16(afA[i], bf0[j], acc[i + 4][j], 0, 0, 0);
        __builtin_amdgcn_s_setprio(0);

        // phase 3: (mh1, kh1)
#pragma unroll
        for (int i = 0; i < 4; ++i) afB[i] = *(const short8*)(Ab + arow + (i + 4) * 2048 + so1);
        __builtin_amdgcn_s_setprio(1);
#pragma unroll
        for (int i = 0; i < 4; ++i)
#pragma unroll
            for (int j = 0; j < 4; ++j)
                acc[i + 4][j] = __builtin_amdgcn_mfma_f32_16x16x32_bf16(afB[i], bf1[j], acc[i + 4][j], 0, 0, 0);
        __builtin_amdgcn_s_setprio(0);

        // all my ds_reads done -> barrier frees buf[cb] for overwrite
        asm volatile("s_waitcnt lgkmcnt(0)" ::: "memory");
        __builtin_amdgcn_s_barrier();
        if (ks < GSTEPS - 2) {
            STAGE(cb);                              // step ks+2 into the freed buffer
            asm volatile("s_waitcnt vmcnt(8)" ::: "memory");   // step ks+1 landed; 8 in flight
        } else if (ks == GSTEPS - 2) {
            asm volatile("s_waitcnt vmcnt(0)" ::: "memory");   // tail: last step's loads
        }
        __builtin_amdgcn_s_barrier();
    }

    // epilogue: raw fp32 partial; C/D layout: col = lane&15, row = quad*4 + reg
    float* Cz = Cp + (size_t)blockIdx.z * ((size_t)M_DIM * N_DIM);
#pragma unroll
    for (int i = 0; i < 8; ++i) {
        const int row = m0 + wm * 128 + i * 16 + quad * 4;
#pragma unroll
        for (int j = 0; j < 4; ++j) {
            const int col = n0 + wn * 64 + j * 16 + r16;
#pragma unroll
            for (int r = 0; r < 4; ++r)
                Cz[(size_t)(row + r) * N_DIM + col] = acc[i][j][r];
        }
    }
}

// ---- 4. combine: out = tanh(C0 + C1 + bias), float4 vectorized ----
__global__ void combine_kernel(const float* __restrict__ Cp,
                               const float* __restrict__ bias,
                               float* __restrict__ out) {
    size_t t = (size_t)blockIdx.x * 256 + threadIdx.x;       // per float4
    const size_t stride = (size_t)M_DIM * N_DIM / 4;
    float4 a = ((const float4*)Cp)[t];
    float4 b = ((const float4*)Cp)[t + stride];
    float4 bv = ((const float4*)bias)[t & (N_DIM / 4 - 1)];
    float4 o;
    o.x = tanhf(a.x + b.x + bv.x);
    o.y = tanhf(a.y + b.y + bv.y);
    o.z = tanhf(a.z + b.z + bv.z);
    o.w = tanhf(a.w + b.w + bv.w);
    ((float4*)out)[t] = o;
}

extern "C" void kernel_launch(void* const* d_in, const int* in_sizes, int n_in,
                              void* d_out, int out_size, void* d_ws, size_t ws_size,
                              hipStream_t stream) {
    const float* x    = (const float*)d_in[0];
    const float* kv   = (const float*)d_in[1];
    const float* bias = (const float*)d_in[2];
    const int*   ind  = (const int*)d_in[3];
    const int nnz = in_sizes[1];

    unsigned short* Wbt = (unsigned short*)d_ws;                        // bf16 W^T (N x KP)
    unsigned short* xb  = (unsigned short*)((char*)d_ws + XB_OFFSET);   // bf16 x (M x KP)
    float* Cp = (float*)((char*)d_ws + CP_OFFSET);                      // 2 x 33.55 MB partials

    // 1. zero bf16 W^T (incl. K-pad)
    hipMemsetAsync(Wbt, 0, WBT_BYTES, stream);
    // 2. scatter-add straight into bf16 W^T (CAS on 16-bit halves)
    scatter_bf16_kernel<<<(nnz + 255) / 256, 256, 0, stream>>>(
        kv, ind, (unsigned int*)Wbt, nnz);
    // 3. x fp32 -> bf16 (writes its own K-pad zeros)
    convert_kernel<<<(M_DIM * (KP / 8)) / 256, 256, 0, stream>>>(x, xb);
    // 4. split-K=2 GEMM partials, 256x256 tiles, 1 WG/CU
    gemm256_kernel<<<dim3(N_DIM / 256, M_DIM / 256, 2), 512, 0, stream>>>(
        xb, Wbt, Cp);
    // 5. combine + bias + tanh
    combine_kernel<<<(M_DIM * N_DIM) / (256 * 4), 256, 0, stream>>>(
        Cp, bias, (float*)d_out);
}

// Round 2
// 662.903 us; speedup vs baseline: 1.3046x; 1.0789x over previous
//
#include <hip/hip_runtime.h>
#include <cstdint>
#include <cstddef>

#define M_DIM 2048
#define N_DIM 4096
#define K_DIM 20000
#define KP    20480                 /* K padded to multiple of 64 (zero-filled) */
#define KZ    10240                 /* K per split-K plane (2 planes) */
#define NITER 80                    /* (KZ/64) tiles / 2 tiles per iter */
#define WBT_BYTES  167772160UL      /* 4096*20480*2 : bf16 W^T (N x KP) */
#define XB_OFFSET  167772160UL      /* bf16 x (M x KP) after Wbt */
#define CP_OFFSET  251658240UL      /* 2x fp32 C-partials after xb */

typedef __attribute__((ext_vector_type(8))) short short8;
typedef __attribute__((ext_vector_type(4))) float float4v;
typedef __attribute__((ext_vector_type(8))) unsigned short ushort8;

__device__ __forceinline__ unsigned short f2bf_rne(float f) {
    union { float f; unsigned int u; } v; v.f = f;
    unsigned int u = v.u;
    u += 0x7FFFu + ((u >> 16) & 1u);   // round-to-nearest-even
    return (unsigned short)(u >> 16);
}

__device__ __forceinline__ float bf2f(unsigned short h) {
    union { unsigned int u; float f; } v;
    v.u = ((unsigned int)h) << 16;
    return v.f;
}

__device__ __forceinline__ void gload_lds16(const void* g, void* l) {
    __builtin_amdgcn_global_load_lds(
        (const __attribute__((address_space(1))) void*)g,
        (__attribute__((address_space(3))) void*)l, 16, 0, 0);
}

// ---- 1. scatter-add COO directly into bf16 W^T (N_DIM x KP row-major) ----
__global__ void scatter_bf16_kernel(const float* __restrict__ kv,
                                    const int* __restrict__ ind,
                                    unsigned int* __restrict__ W, int nnz) {
    int t = blockIdx.x * blockDim.x + threadIdx.x;
    if (t >= nnz) return;
    int r = ind[2 * t];      // input_dim index (K)
    int c = ind[2 * t + 1];  // units index (N)
    float v = kv[t];
    size_t elem = (size_t)c * KP + r;      // bf16 element index in W^T
    unsigned int* word = &W[elem >> 1];
    const bool hi = (elem & 1) != 0;       // KP even -> rows never straddle words
    unsigned int old = __atomic_load_n(word, __ATOMIC_RELAXED);
    unsigned int assumed;
    do {
        assumed = old;
        unsigned short h = hi ? (unsigned short)(assumed >> 16)
                              : (unsigned short)(assumed & 0xFFFFu);
        unsigned short nh = f2bf_rne(bf2f(h) + v);
        unsigned int nw = hi ? ((assumed & 0x0000FFFFu) | ((unsigned int)nh << 16))
                             : ((assumed & 0xFFFF0000u) | (unsigned int)nh);
        old = atomicCAS(word, assumed, nw);
    } while (old != assumed);
}

// ---- 2. fp32 -> bf16 convert for x, writes K-pad zeros itself ----
__global__ void convert_kernel(const float* __restrict__ src,
                               unsigned short* __restrict__ dst) {
    size_t t = (size_t)blockIdx.x * 256 + threadIdx.x;
    int row = (int)(t / 2560);
    int c8  = (int)(t % 2560);
    ushort8 o;
    if (c8 < 2500) {
        const float4* sv = (const float4*)(src + (size_t)row * K_DIM + (size_t)c8 * 8);
        float4 a = sv[0];
        float4 b = sv[1];
        o[0] = f2bf_rne(a.x); o[1] = f2bf_rne(a.y);
        o[2] = f2bf_rne(a.z); o[3] = f2bf_rne(a.w);
        o[4] = f2bf_rne(b.x); o[5] = f2bf_rne(b.y);
        o[6] = f2bf_rne(b.z); o[7] = f2bf_rne(b.w);
    } else {
        o = (ushort8)0;
    }
    *(ushort8*)(dst + (size_t)row * KP + (size_t)c8 * 8) = o;
}

// ---- 3. 256x256-tile split-K=2 GEMM, m201-style 8-phase schedule ----
// A: M x KP bf16 row-major, Bt: N x KP bf16 row-major.
// 512 thr = 8 waves (2Mx4N), per-wave 128x64, BK=64, 2 K-tiles per iter.
// LDS 128 KiB, buffer = A[kh][row][32k] (2x16KB) + B[kh][row][32k] (2x16KB).
// 64B rows => a wave's fragment read (quad=chunk, r16=row) is a contiguous
// 1KB block: conflict-free with NO swizzle; staging is linear.
// Per phase: {ds_read subtile, stage one 16KB quarter (2 gloads), s_barrier,
// lgkmcnt(0) (reads landed during barrier), setprio(1) 16 MFMA setprio(0),
// [vmcnt(8) at even phases], s_barrier}.  vmcnt never drains in main loop.
__global__ __launch_bounds__(512, 2) void gemm256_kernel(
    const unsigned short* __restrict__ A,
    const unsigned short* __restrict__ Bt,
    float* __restrict__ Cp) {

    __shared__ unsigned short L[65536];    // 131072 B

    const int t    = threadIdx.x;
    const int w    = t >> 6;
    const int l    = t & 63;
    const int quad = l >> 4;
    const int r16  = l & 15;
    const int wm   = w >> 2;               // 0..1
    const int wn   = w & 3;                // 0..3

    const int m0 = blockIdx.y * 256;
    const int n0 = blockIdx.x * 256;
    const size_t k0 = (size_t)blockIdx.z * KZ;

    // staging: per quarter (16KB = 256 rows x 64B), wave w writes rows
    // w*32..w*32+31 via 2 gloads (q=0,1); lane l -> row +(l>>2), chunk l&3.
    const int l4 = l >> 2;
    const int c4 = l & 3;
    const unsigned short* pA0 = A  + (size_t)(m0 + w * 32 + l4) * KP + k0 + c4 * 8;
    const unsigned short* pA1 = pA0 + (size_t)16 * KP;
    const unsigned short* pB0 = Bt + (size_t)(n0 + w * 32 + l4) * KP + k0 + c4 * 8;
    const unsigned short* pB1 = pB0 + (size_t)16 * KP;

    char* Lb = (char*)L;
    const int wdst = w << 11;              // wave's 2KB within a quarter

    // buffer layout (byte offsets): buf b at b*65536
    //   A kh0 [0,16K)  A kh1 [16K,32K)  B kh0 [32K,48K)  B kh1 [48K,64K)
#define STAGE_A(REG) do { \
    gload_lds16(pA0, Lb + (REG) + wdst); \
    gload_lds16(pA1, Lb + (REG) + wdst + 1024); \
    pA0 += 32; pA1 += 32; } while (0)
#define STAGE_B(REG) do { \
    gload_lds16(pB0, Lb + (REG) + wdst); \
    gload_lds16(pB1, Lb + (REG) + wdst + 1024); \
    pB0 += 32; pB1 += 32; } while (0)

    // fragment offsets within a (buf,kh) A-slab / buffer
    const int aoff = (wm * 128 + r16) * 64 + quad * 16;          // + mh*4096 + i*1024
    const int boff = 32768 + (wn * 64 + r16) * 64 + quad * 16;   // + j*1024 (kh folded in base)

    float4v acc[8][4];
#pragma unroll
    for (int i = 0; i < 8; ++i)
#pragma unroll
        for (int j = 0; j < 4; ++j)
            acc[i][j] = (float4v){0.f, 0.f, 0.f, 0.f};

    short8 bfr[4], af[4];

#define VM8 asm volatile("s_waitcnt vmcnt(8)" ::: "memory")
#define VMNONE ((void)0)

    // BASEOFF = buf*65536 + kh*16384 (A slab base; B slab = +32768 via boff)
#define PHASE(BASEOFF, MH, LOADB, STG, VM) do { \
    const char* base_ = Lb + (BASEOFF); \
    if (LOADB) { \
        _Pragma("unroll") \
        for (int j = 0; j < 4; ++j) \
            bfr[j] = *(const short8*)(base_ + boff + j * 1024); \
    } \
    _Pragma("unroll") \
    for (int i = 0; i < 4; ++i) \
        af[i] = *(const short8*)(base_ + aoff + (MH) * 4096 + i * 1024); \
    STG; \
    __builtin_amdgcn_s_barrier(); \
    asm volatile("s_waitcnt lgkmcnt(0)" ::: "memory"); \
    __builtin_amdgcn_s_setprio(1); \
    _Pragma("unroll") \
    for (int i = 0; i < 4; ++i) \
        _Pragma("unroll") \
        for (int j = 0; j < 4; ++j) \
            acc[(MH) * 4 + i][j] = __builtin_amdgcn_mfma_f32_16x16x32_bf16( \
                af[i], bfr[j], acc[(MH) * 4 + i][j], 0, 0, 0); \
    __builtin_amdgcn_s_setprio(0); \
    VM; \
    __builtin_amdgcn_s_barrier(); \
} while (0)

    // prologue: tile0 full + tile1 kh0 (12 loads); wait tile0.kh0 (oldest 4)
    STAGE_A(0);     STAGE_B(32768);
    STAGE_A(16384); STAGE_B(49152);
    STAGE_A(65536); STAGE_B(98304);
    asm volatile("s_waitcnt vmcnt(8)" ::: "memory");
    __builtin_amdgcn_s_barrier();

    // main loop: iter computes tiles 2i (buf0) and 2i+1 (buf1).
    // staging stream per iter: P1 t(2i+1).A1, P2 t(2i+1).B1, P3 t(2i+2).A0,
    // P4 .B0, P5 .A1, P6 .B1, P7 t(2i+3).A0, P8 .B0 — each lands in a slab
    // freed one-or-more barriers earlier; vmcnt(8) at even phases guarantees
    // the next odd phase's slab (staged 4 phases ago) has landed.
    // Final iter stages past the K range: reads stay inside the workspace
    // (xb/Cp follow Wbt/xb), data never consumed.
#pragma unroll 1
    for (int it = 0; it < NITER; ++it) {
        PHASE(0,     0, true,  STAGE_A(81920),  VMNONE);   // P1: buf0 kh0, mh0
        PHASE(0,     1, false, STAGE_B(114688), VM8);      // P2: buf0 kh0, mh1
        PHASE(16384, 0, true,  STAGE_A(0),      VMNONE);   // P3: buf0 kh1, mh0
        PHASE(16384, 1, false, STAGE_B(32768),  VM8);      // P4: buf0 kh1, mh1
        PHASE(65536, 0, true,  STAGE_A(16384),  VMNONE);   // P5: buf1 kh0, mh0
        PHASE(65536, 1, false, STAGE_B(49152),  VM8);      // P6: buf1 kh0, mh1
        PHASE(81920, 0, true,  STAGE_A(65536),  VMNONE);   // P7: buf1 kh1, mh0
        PHASE(81920, 1, false, STAGE_B(98304),  VM8);      // P8: buf1 kh1, mh1
    }
    // drain in-flight LDS DMA before wave exit (LDS could be reallocated)
    asm volatile("s_waitcnt vmcnt(0)" ::: "memory");

    // epilogue: raw fp32 partial; C/D layout: col = lane&15, row = quad*4 + reg
    float* Cz = Cp + (size_t)blockIdx.z * ((size_t)M_DIM * N_DIM);
#pragma unroll
    for (int i = 0; i < 8; ++i) {
        const int row = m0 + wm * 128 + i * 16 + quad * 4;
#pragma unroll
        for (int j = 0; j < 4; ++j) {
            const int col = n0 + wn * 64 + j * 16 + r16;
#pragma unroll
            for (int r = 0; r < 4; ++r)
                Cz[(size_t)(row + r) * N_DIM + col] = acc[i][j][r];
        }
    }
#undef PHASE
#undef STAGE_A
#undef STAGE_B
#undef VM8
#undef VMNONE
}

// ---- 4. combine: out = tanh(C0 + C1 + bias), float4 vectorized ----
__global__ void combine_kernel(const float* __restrict__ Cp,
                               const float* __restrict__ bias,
                               float* __restrict__ out) {
    size_t t = (size_t)blockIdx.x * 256 + threadIdx.x;       // per float4
    const size_t stride = (size_t)M_DIM * N_DIM / 4;
    float4 a = ((const float4*)Cp)[t];
    float4 b = ((const float4*)Cp)[t + stride];
    float4 bv = ((const float4*)bias)[t & (N_DIM / 4 - 1)];
    float4 o;
    o.x = tanhf(a.x + b.x + bv.x);
    o.y = tanhf(a.y + b.y + bv.y);
    o.z = tanhf(a.z + b.z + bv.z);
    o.w = tanhf(a.w + b.w + bv.w);
    ((float4*)out)[t] = o;
}

extern "C" void kernel_launch(void* const* d_in, const int* in_sizes, int n_in,
                              void* d_out, int out_size, void* d_ws, size_t ws_size,
                              hipStream_t stream) {
    const float* x    = (const float*)d_in[0];
    const float* kv   = (const float*)d_in[1];
    const float* bias = (const float*)d_in[2];
    const int*   ind  = (const int*)d_in[3];
    const int nnz = in_sizes[1];

    unsigned short* Wbt = (unsigned short*)d_ws;                        // bf16 W^T (N x KP)
    unsigned short* xb  = (unsigned short*)((char*)d_ws + XB_OFFSET);   // bf16 x (M x KP)
    float* Cp = (float*)((char*)d_ws + CP_OFFSET);                      // 2 x 33.55 MB partials

    // 1. zero bf16 W^T (incl. K-pad)
    hipMemsetAsync(Wbt, 0, WBT_BYTES, stream);
    // 2. scatter-add straight into bf16 W^T (CAS on 16-bit halves)
    scatter_bf16_kernel<<<(nnz + 255) / 256, 256, 0, stream>>>(
        kv, ind, (unsigned int*)Wbt, nnz);
    // 3. x fp32 -> bf16 (writes its own K-pad zeros)
    convert_kernel<<<(M_DIM * (KP / 8)) / 256, 256, 0, stream>>>(x, xb);
    // 4. split-K=2 GEMM partials, 256x256 tiles, 1 WG/CU
    gemm256_kernel<<<dim3(N_DIM / 256, M_DIM / 256, 2), 512, 0, stream>>>(
        xb, Wbt, Cp);
    // 5. combine + bias + tanh
    combine_kernel<<<(M_DIM * N_DIM) / (256 * 4), 256, 0, stream>>>(
        Cp, bias, (float*)d_out);
}